// Round 2
// baseline (221.033 us; speedup 1.0000x reference)
//
#include <hip/hip_runtime.h>
#include <hip/hip_bf16.h>

#define NN 128
#define TT 256
#define EE 6
#define DD 10
#define TE (TT*EE)          // 1536 floats per (j) slice
#define F4 (TE/4)           // 384 float4 per slice
#define C1 15               // input1 inner dim: 1+E+E+2
#define NBLK (NN*8)         // pair_reduce grid size = 1024

// Kernel 0: w[j*TE + t*E + e] = 1 / input1[j,t,7+e]^2 ; also zero the
// completion counter (ws is poisoned 0xAA before every launch).
__global__ void prep_w(const float* __restrict__ input1, float* __restrict__ w,
                       unsigned int* __restrict__ cnt) {
    int idx = blockIdx.x * 256 + threadIdx.x;      // over N*T*E = 196608
    if (idx == 0) *cnt = 0u;
    if (idx < NN * TE) {
        int f = idx % TE;
        int j = idx / TE;
        int t = f / EE, e = f % EE;
        float v = input1[(j * TT + t) * C1 + 1 + EE + e];
        w[idx] = 1.0f / (v * v);
    }
}

// Kernel 1 (fused): raw[i,j] = sum_{t,e} (yij[i,j,t,e]-yi[j,t,e])^2 * w[j,t,e]
// grid (j=128, ig=8), 256 threads = 4 waves. Wave wv handles i = ig*16 + wv*4 + k.
// yi[j]/w[j] fragments live in registers (6 float4 each), reused across 16 i.
// Last block to finish computes the final scalar loss (no extra dispatch).
__launch_bounds__(256)
__global__ void pair_reduce_finalize(const float* __restrict__ yij,
                                     const float* __restrict__ yi,
                                     const float* __restrict__ w,
                                     const float* __restrict__ samples,
                                     float* __restrict__ raw,
                                     unsigned int* __restrict__ cnt,
                                     float* __restrict__ out) {
    const int j    = blockIdx.x;
    const int i0   = blockIdx.y * 16;
    const int tid  = threadIdx.x;
    const int wv   = tid >> 6;
    const int lane = tid & 63;

    // Stage yi[j], w[j] fragments into registers: f4-index = lane + 64*m
    const float4* m4 = (const float4*)(yi + (size_t)j * TE);
    const float4* w4 = (const float4*)(w  + (size_t)j * TE);
    float4 ym[6], wm[6];
#pragma unroll
    for (int m = 0; m < 6; ++m) {
        ym[m] = m4[lane + 64 * m];
        wm[m] = w4[lane + 64 * m];
    }

#pragma unroll
    for (int k = 0; k < 4; ++k) {
        const int i = i0 + wv * 4 + k;
        const float4* a = (const float4*)(yij + ((size_t)i * NN + j) * TE);
        float s = 0.0f;
#pragma unroll
        for (int m = 0; m < 6; ++m) {
            float4 x = a[lane + 64 * m];
            float d0 = x.x - ym[m].x; s += d0 * d0 * wm[m].x;
            float d1 = x.y - ym[m].y; s += d1 * d1 * wm[m].y;
            float d2 = x.z - ym[m].z; s += d2 * d2 * wm[m].z;
            float d3 = x.w - ym[m].w; s += d3 * d3 * wm[m].w;
        }
#pragma unroll
        for (int off = 32; off > 0; off >>= 1) s += __shfl_down(s, off);
        if (lane == 0) raw[(size_t)i * NN + j] = s;
    }

    // ---- last-block-done finalize ----
    __shared__ int isLast;
    __syncthreads();                 // all waves finished their raw writes
    if (tid == 0) {
        __threadfence();             // make raw visible device-wide (release)
        unsigned int old = atomicAdd(cnt, 1u);
        isLast = (old == NBLK - 1) ? 1 : 0;
    }
    __syncthreads();
    if (!isLast) return;
    __threadfence();                 // acquire all blocks' raw writes

    __shared__ float smp[NN * DD];   // 1280 floats
    for (int q = tid; q < NN * DD; q += 256) smp[q] = samples[q];
    __syncthreads();

    float acc = 0.0f;
    for (int it = 0; it < 64; ++it) {
        const int p  = it * 256 + tid;     // coalesced over raw[p]
        const int i  = p >> 7, jj = p & 127;
        float S = 0.0f;
#pragma unroll
        for (int d = 0; d < DD; ++d) {
            float dd = smp[jj * DD + d] - smp[i * DD + d];
            S += dd * dd;
        }
        S *= (1.0f / DD);
        float sec = (raw[p] + raw[jj * NN + i]) * (0.5f / (TE * 10.0f));
        acc += fabsf(S - sec);
    }
#pragma unroll
    for (int off = 32; off > 0; off >>= 1) acc += __shfl_down(acc, off);
    __shared__ float ls[4];
    if ((tid & 63) == 0) ls[tid >> 6] = acc;
    __syncthreads();
    if (tid == 0)
        out[0] = (ls[0] + ls[1] + ls[2] + ls[3]) * (1.0f / (NN * NN));
}

extern "C" void kernel_launch(void* const* d_in, const int* in_sizes, int n_in,
                              void* d_out, int out_size, void* d_ws, size_t ws_size,
                              hipStream_t stream) {
    // inputs: merged, y_pred_i, y_pred_ij, input1, samples, labels
    const float* y_pred_i  = (const float*)d_in[1];
    const float* y_pred_ij = (const float*)d_in[2];
    const float* input1    = (const float*)d_in[3];
    const float* samples   = (const float*)d_in[4];
    float* out = (float*)d_out;

    // ws layout: w (N*TE floats) | raw (N*N floats) | counter (1 uint)
    float* w   = (float*)d_ws;
    float* raw = w + (size_t)NN * TE;
    unsigned int* cnt = (unsigned int*)(raw + (size_t)NN * NN);

    prep_w<<<(NN * TE + 255) / 256, 256, 0, stream>>>(input1, w, cnt);

    dim3 grid(NN, 8);
    pair_reduce_finalize<<<grid, 256, 0, stream>>>(y_pred_ij, y_pred_i, w,
                                                   samples, raw, cnt, out);
}